// Round 13
// baseline (12817.775 us; speedup 1.0000x reference)
//
#include <hip/hip_runtime.h>

// APDL_RNN: allpass-delay LSTM. B=32, T=8192, I=1, H=256, OS_FACTOR=1.5 -> coeff=1/3.
// 128 WGs = 32 batches x 4 quartet members; 512 threads/WG (8 waves).
// Each WG owns 64 hidden units; gate rows K-split across lane pairs: 128 fp32
// weights/thread as 32 pinned floatx4. hs padded (+HPAD): 0 bank conflicts.
// Parity-dbuf hs2, ONE barrier/step. R12 packing: 2 self-tagged fp32 / 8B slot.
//
// Sync model (R5-R12, 7-experiment): per-step cost = V (agent-store -> IC visible)
// + C (poll observation = load latency + overshoot) + compute. R12 proved message
// count irrelevant (FETCH halved, dur flat) -> latency-bound.
// R13 attacks C and V:
//  (a) staggered dual pollers: lanes 128-223 mirror lanes 0-95 after s_sleep(5)
//      (~320cy). First catcher stages + lgkmcnt(0) + LDS done-stamp; other exits
//      on done-check. Tail overshoot ~700 -> ~350+150. In-flight polls = 192/WG
//      (same as proven R5, NOT R10's 768).
//  (b) publish via non-returning atomic exchange (RMW commits at IC point;
//      may cut V vs relaxed store write-back).

#define Bn 32
#define Tn 8192
#define Hn 256
#define HPAD 136  // second K-half offset in padded hs

typedef float floatx4 __attribute__((ext_vector_type(4)));

static constexpr float kCoeff = 1.0f / 3.0f;  // (1-alpha)/(1+alpha), alpha=0.5

__device__ __forceinline__ float sigf(float x) {
  return __builtin_amdgcn_rcpf(1.0f + __expf(-x));
}
__device__ __forceinline__ float tanhf_fast(float x) {
  return 1.0f - 2.0f * __builtin_amdgcn_rcpf(1.0f + __expf(2.0f * x));
}
__device__ __forceinline__ float pick4(int d, float v0, float v1, float v2, float v3) {
  float r = (d == 0) ? v0 : v1;
  r = (d == 2) ? v2 : r;
  r = (d == 3) ? v3 : r;
  return r;
}
// embed tag in low 9 mantissa bits (round-to-nearest on the kept part)
__device__ __forceinline__ unsigned tagf(float v, unsigned tg) {
  return ((__float_as_uint(v) + 256u) & ~511u) | tg;
}

// Dual-poller body: spin on the packed slot until both dwords carry tag, OR until
// the partner poller's done-stamp appears. Catcher stages float2 then stamps.
__device__ __forceinline__ void poll_stage(const unsigned long long* pa, int* dn,
                                           float* dst, unsigned tg, int t) {
  for (;;) {
    unsigned long long pk =
        __hip_atomic_load(pa, __ATOMIC_RELAXED, __HIP_MEMORY_SCOPE_AGENT);
    unsigned lo = (unsigned)pk, hi = (unsigned)(pk >> 32);
    if (!(((lo ^ tg) & 511u) | ((hi ^ tg) & 511u))) {
      *(float2*)dst = make_float2(__uint_as_float(lo), __uint_as_float(hi));
      asm volatile("s_waitcnt lgkmcnt(0)" ::: "memory");  // stage committed...
      __hip_atomic_store(dn, t, __ATOMIC_RELAXED,
                         __HIP_MEMORY_SCOPE_WORKGROUP);   // ...before stamp
      return;
    }
    if (__hip_atomic_load(dn, __ATOMIC_RELAXED, __HIP_MEMORY_SCOPE_WORKGROUP) == t)
      return;  // partner caught & staged
  }
}

// d_ws: ull pub[32][2][128] = 65536 B (2 self-tagged fp32 per slot); re-zeroed
// every launch so stale tags can't match.
__global__ void init_ws(unsigned int* ws) {
  int i = blockIdx.x * 256 + threadIdx.x;
  if (i < 16384) ws[i] = 0;
}

#define LOADW(i) floatx4 w##i = *(const floatx4*)(wrow + 4 * (i))
#define PINW(i) asm volatile("" : "+v"(w##i))
#define ACC8(i, j, K)                                           \
  {                                                             \
    floatx4 p = *(const floatx4*)&hsp[(K)];                     \
    floatx4 q = *(const floatx4*)&hsp[(K) + 4];                 \
    a0 = fmaf(w##i[0], p[0], a0); a1 = fmaf(w##i[1], p[1], a1); \
    a2 = fmaf(w##i[2], p[2], a2); a3 = fmaf(w##i[3], p[3], a3); \
    a4 = fmaf(w##j[0], q[0], a4); a5 = fmaf(w##j[1], q[1], a5); \
    a6 = fmaf(w##j[2], q[2], a6); a7 = fmaf(w##j[3], q[3], a7); \
  }

__global__ __launch_bounds__(512, 2) void apdl_rnn(
    const float* __restrict__ x, const float* __restrict__ W_ih,
    const float* __restrict__ W_hh, const float* __restrict__ b_ih,
    const float* __restrict__ b_hh, float* __restrict__ out,
    unsigned long long* __restrict__ pub) {
  const int bid = blockIdx.x;
  const int w = bid >> 5;    // quartet member 0..3
  const int b = bid & 31;    // batch
  const int tid = (int)threadIdx.x;
  const int hf = tid & 1;    // K-half
  const int p = tid >> 1;    // row-pair index 0..255
  const int g = p & 3;       // gate: 0=i 1=f 2=g 3=o
  const int ul = p >> 2;     // local hidden unit 0..63
  const int u = w * 64 + ul; // global hidden unit 0..255
  const int row = g * Hn + u;

  __shared__ __align__(16) float xs[Tn];            // this batch's x sequence, 32KB
  __shared__ __align__(16) float hs2[2][2 * HPAD];  // parity-dbuf padded ap_h staging
  __shared__ int done[96];                          // per-slot catch stamp (monotonic)

  for (int i = tid; i < Tn; i += 512) xs[i] = x[b * Tn + i];
  if (tid < 96) done[tid] = 0;

  // this thread's half-row: 32 x floatx4, pinned once (unified VGPR/AGPR file)
  const float* wrow = W_hh + row * Hn + hf * 128;
  LOADW(0);  LOADW(1);  LOADW(2);  LOADW(3);  LOADW(4);  LOADW(5);  LOADW(6);  LOADW(7);
  LOADW(8);  LOADW(9);  LOADW(10); LOADW(11); LOADW(12); LOADW(13); LOADW(14); LOADW(15);
  LOADW(16); LOADW(17); LOADW(18); LOADW(19); LOADW(20); LOADW(21); LOADW(22); LOADW(23);
  LOADW(24); LOADW(25); LOADW(26); LOADW(27); LOADW(28); LOADW(29); LOADW(30); LOADW(31);
  asm volatile("s_waitcnt vmcnt(0)" ::: "memory");
  PINW(0);  PINW(1);  PINW(2);  PINW(3);  PINW(4);  PINW(5);  PINW(6);  PINW(7);
  PINW(8);  PINW(9);  PINW(10); PINW(11); PINW(12); PINW(13); PINW(14); PINW(15);
  PINW(16); PINW(17); PINW(18); PINW(19); PINW(20); PINW(21); PINW(22); PINW(23);
  PINW(24); PINW(25); PINW(26); PINW(27); PINW(28); PINW(29); PINW(30); PINW(31);

  const float wih = W_ih[row];
  const float bias = b_ih[row] + b_hh[row];

  unsigned long long* mypub = pub + b * 2 * 128;  // [parity][slot]; slot = unit/2

  // primary pollers: lanes 0..95; secondary (staggered) pollers: lanes 128..223.
  const bool prim = (tid < 96);
  const bool secd = (tid >= 128 && tid < 224);
  const int pi = prim ? tid : (secd ? tid - 128 : 0);        // poll index 0..95
  const int slot = (pi < w * 32) ? pi : pi + 32;             // skip own chunk

  float s1_h = 0.f, s1_c = 0.f, ap_h = 0.f, ap_c = 0.f;

  for (int t = 0; t < Tn; ++t) {
    // ---- acquire ap_h(t) for remote units: staggered dual poll ----
    if (t == 0) {
      if (tid < 128) {
        const int u0 = 2 * tid, idx0 = u0 + ((u0 >> 7) << 3);
        *(float2*)&hs2[0][idx0] = make_float2(0.f, 0.f);  // ap(0) = 0
      }
    } else if (prim || secd) {
      if (secd) __builtin_amdgcn_s_sleep(5);  // ~320cy stagger
      const int u0 = 2 * slot, idx0 = u0 + ((u0 >> 7) << 3);
      poll_stage(mypub + (t & 1) * 128 + slot, &done[pi], &hs2[t & 1][idx0],
                 (unsigned)t & 511u, t);
    }
    __syncthreads();  // single barrier per step (parity dbuf)

    // ---- half-row dot: 128 fp32 MACs, weights register-resident ----
    const float* hsp = &hs2[t & 1][hf * HPAD];
    float a0 = 0.f, a1 = 0.f, a2 = 0.f, a3 = 0.f;
    float a4 = 0.f, a5 = 0.f, a6 = 0.f, a7 = 0.f;
    ACC8(0, 1, 0);     ACC8(2, 3, 8);     ACC8(4, 5, 16);    ACC8(6, 7, 24);
    ACC8(8, 9, 32);    ACC8(10, 11, 40);  ACC8(12, 13, 48);  ACC8(14, 15, 56);
    ACC8(16, 17, 64);  ACC8(18, 19, 72);  ACC8(20, 21, 80);  ACC8(22, 23, 88);
    ACC8(24, 25, 96);  ACC8(26, 27, 104); ACC8(28, 29, 112); ACC8(30, 31, 120);
    float half = ((a0 + a1) + (a2 + a3)) + ((a4 + a5) + (a6 + a7));
    float dot = half + __shfl_xor(half, 1);  // combine K-halves
    float raw = dot + xs[t] * wih + bias;

    // ---- activate own gate, exchange across the 4 gate pairs ----
    float act = (g == 2) ? tanhf_fast(raw) : sigf(raw);
    float v1 = __shfl_xor(act, 2);
    float v2 = __shfl_xor(act, 4);
    float v3 = __shfl_xor(act, 6);
    float ai = pick4(g,     act, v1, v2, v3);  // sigmoid(i)
    float af = pick4(g ^ 1, act, v1, v2, v3);  // sigmoid(f)
    float ag = pick4(g ^ 2, act, v1, v2, v3);  // tanh(g)
    float ao = pick4(g ^ 3, act, v1, v2, v3);  // sigmoid(o)

    float c_new = af * ap_c + ai * ag;
    float h_new = ao * tanhf_fast(c_new);

    if (t < Tn - 1) {
      // ---- allpass h-update + packed publish FIRST (latency-critical) ----
      float nh = kCoeff * (h_new - ap_h) + s1_h;
      if (g == 3 && hf == 0) {  // lanes tid = 8u+6: one per unit
        unsigned vb = tagf(nh, (unsigned)(t + 1) & 511u);  // self-tagged bits
        unsigned pb = __shfl_xor(vb, 8);                   // partner unit's bits
        if ((tid & 15) == 6) {  // even-unit lane publishes the pair
          const int s = w * 32 + (tid >> 4);  // global slot = u/2
          unsigned long long pk = (unsigned long long)vb |
                                  ((unsigned long long)pb << 32);
          // non-returning RMW: commits at the IC coherence point
          __hip_atomic_exchange(mypub + ((t + 1) & 1) * 128 + s, pk,
                                __ATOMIC_RELAXED, __HIP_MEMORY_SCOPE_AGENT);
          const int u0 = 2 * s;
          const int idx0 = u0 + ((u0 >> 7) << 3);
          *(float2*)&hs2[(t + 1) & 1][idx0] =           // own WG (LDS shortcut)
              make_float2(__uint_as_float(vb), __uint_as_float(pb));
        }
      }
      float nc = kCoeff * (c_new - ap_c) + s1_c;
      s1_h = h_new; s1_c = c_new; ap_h = nh; ap_c = nc;
    } else {
      if (g == 0 && hf == 0)      out[201326592 + b * 512 + u] = ap_h;        // ap_final h
      else if (g == 1 && hf == 0) out[201326592 + b * 512 + 256 + u] = ap_c;  // ap_final c
    }

    // ---- outputs: (y, states_h, states_c) fp32, fire-and-forget ----
    int o = (b * Tn + t) * Hn + u;
    if (hf == 0) {
      if (g == 0)      out[o] = h_new;             // y
      else if (g == 2) out[67108864 + o] = h_new;  // states h
      else if (g == 1) out[134217728 + o] = c_new; // states c
    }
    // no trailing barrier: parity dbuf + publish-after-barrier make it safe
  }
}

extern "C" void kernel_launch(void* const* d_in, const int* in_sizes, int n_in,
                              void* d_out, int out_size, void* d_ws, size_t ws_size,
                              hipStream_t stream) {
  const float* x = (const float*)d_in[0];
  const float* W_ih = (const float*)d_in[1];
  const float* W_hh = (const float*)d_in[2];
  const float* b_ih = (const float*)d_in[3];
  const float* b_hh = (const float*)d_in[4];
  float* out = (float*)d_out;
  unsigned long long* pub = (unsigned long long*)d_ws;

  init_ws<<<64, 256, 0, stream>>>((unsigned int*)d_ws);  // reset tags every launch
  apdl_rnn<<<128, 512, 0, stream>>>(x, W_ih, W_hh, b_ih, b_hh, out, pub);
}

// Round 14
// 8794.688 us; speedup vs baseline: 1.4574x; 1.4574x over previous
//
#include <hip/hip_runtime.h>

// APDL_RNN: allpass-delay LSTM. B=32, T=8192, I=1, H=256, OS_FACTOR=1.5 -> coeff=1/3.
// R14: 256 WGs = 32 batches x 8 OCTET members; 512 threads/WG (8 waves), 1 WG/CU.
// Each WG owns 32 units (128 gate rows); each row K-split x4: 64 fp32 weights/thread
// as 16 pinned floatx4. Halves the post-barrier dot (512->256 SIMD-cyc) vs R11.
//
// Sync protocol: UNCHANGED from R11/R12 (7-experiment-validated): serial 8B
// __hip_atomic_{store,load}(AGENT) only; self-tagged packed pairs (tag in low 9
// mantissa bits, 2 units / 8B slot); parity-dbuf hs2; ONE barrier/step; publish
// right after allpass-h; own-chunk via LDS shortcut. R13's stagger/exchange and
// all other poll variants regressed — do not touch the protocol.

#define Bn 32
#define Tn 8192
#define Hn 256
#define QP 72  // LDS stride per K-quarter: banks 0/8/16/24 across q -> conflict-free

typedef float floatx4 __attribute__((ext_vector_type(4)));

static constexpr float kCoeff = 1.0f / 3.0f;  // (1-alpha)/(1+alpha), alpha=0.5

__device__ __forceinline__ float sigf(float x) {
  return __builtin_amdgcn_rcpf(1.0f + __expf(-x));
}
__device__ __forceinline__ float tanhf_fast(float x) {
  return 1.0f - 2.0f * __builtin_amdgcn_rcpf(1.0f + __expf(2.0f * x));
}
__device__ __forceinline__ float pick4(int d, float v0, float v1, float v2, float v3) {
  float r = (d == 0) ? v0 : v1;
  r = (d == 2) ? v2 : r;
  r = (d == 3) ? v3 : r;
  return r;
}
// embed tag in low 9 mantissa bits (round-to-nearest on the kept part)
__device__ __forceinline__ unsigned tagf(float v, unsigned tg) {
  return ((__float_as_uint(v) + 256u) & ~511u) | tg;
}
__device__ __forceinline__ int pidx(int u) { return u + ((u >> 6) << 3); }  // pad map

// d_ws: ull pub[32][2][128] = 65536 B (2 self-tagged fp32 per slot); re-zeroed
// every launch so stale tags can't match.
__global__ void init_ws(unsigned int* ws) {
  int i = blockIdx.x * 256 + threadIdx.x;
  if (i < 16384) ws[i] = 0;
}

#define LOADW(i) floatx4 w##i = *(const floatx4*)(wrow + 4 * (i))
#define PINW(i) asm volatile("" : "+v"(w##i))
#define ACC8(i, j, K)                                           \
  {                                                             \
    floatx4 p = *(const floatx4*)&hsp[(K)];                     \
    floatx4 q = *(const floatx4*)&hsp[(K) + 4];                 \
    a0 = fmaf(w##i[0], p[0], a0); a1 = fmaf(w##i[1], p[1], a1); \
    a2 = fmaf(w##i[2], p[2], a2); a3 = fmaf(w##i[3], p[3], a3); \
    a4 = fmaf(w##j[0], q[0], a4); a5 = fmaf(w##j[1], q[1], a5); \
    a6 = fmaf(w##j[2], q[2], a6); a7 = fmaf(w##j[3], q[3], a7); \
  }

__global__ __launch_bounds__(512, 2) void apdl_rnn(
    const float* __restrict__ x, const float* __restrict__ W_ih,
    const float* __restrict__ W_hh, const float* __restrict__ b_ih,
    const float* __restrict__ b_hh, float* __restrict__ out,
    unsigned long long* __restrict__ pub) {
  const int bid = blockIdx.x;
  const int w = bid >> 5;      // octet member 0..7
  const int b = bid & 31;      // batch
  const int tid = (int)threadIdx.x;
  const int q = tid & 3;       // K-quarter: k in [q*64, q*64+64)
  const int r = tid >> 2;      // row index 0..127
  const int g = r & 3;         // gate: 0=i 1=f 2=g 3=o
  const int ul = r >> 2;       // local unit 0..31
  const int u = w * 32 + ul;   // global unit 0..255
  const int row = g * Hn + u;

  __shared__ __align__(16) float xs[Tn];          // this batch's x sequence, 32KB
  __shared__ __align__(16) float hs2[2][4 * QP];  // parity-dbuf quarter-padded ap_h

  for (int i = tid; i < Tn; i += 512) xs[i] = x[b * Tn + i];

  // this thread's quarter-row: 16 x floatx4, pinned once (unified VGPR/AGPR file)
  const float* wrow = W_hh + row * Hn + q * 64;
  LOADW(0);  LOADW(1);  LOADW(2);  LOADW(3);  LOADW(4);  LOADW(5);  LOADW(6);  LOADW(7);
  LOADW(8);  LOADW(9);  LOADW(10); LOADW(11); LOADW(12); LOADW(13); LOADW(14); LOADW(15);
  asm volatile("s_waitcnt vmcnt(0)" ::: "memory");
  PINW(0);  PINW(1);  PINW(2);  PINW(3);  PINW(4);  PINW(5);  PINW(6);  PINW(7);
  PINW(8);  PINW(9);  PINW(10); PINW(11); PINW(12); PINW(13); PINW(14); PINW(15);

  const float wih = W_ih[row];
  const float bias = b_ih[row] + b_hh[row];

  unsigned long long* mypub = pub + b * 2 * 128;  // [parity][slot]; slot = unit/2

  // pollers: lanes 0..111, one remote 8B slot (2 units) each; own 16 slots
  // arrive via the publisher's LDS shortcut (no IC trip).
  const bool poller = (tid < 112);
  const int slot = poller ? (tid < w * 16 ? tid : tid + 16) : 0;  // skip own chunk

  float s1_h = 0.f, s1_c = 0.f, ap_h = 0.f, ap_c = 0.f;

  for (int t = 0; t < Tn; ++t) {
    // ---- acquire ap_h(t) for remote units: serial agent poll (proven) ----
    if (t == 0) {
      if (tid < 128) {
        *(float2*)&hs2[0][pidx(2 * tid)] = make_float2(0.f, 0.f);  // ap(0) = 0
      }
    } else if (poller) {
      const unsigned long long* pa = mypub + (t & 1) * 128 + slot;
      const unsigned tg = (unsigned)t & 511u;
      unsigned long long pk;
      unsigned lo, hi;
      do {
        pk = __hip_atomic_load(pa, __ATOMIC_RELAXED, __HIP_MEMORY_SCOPE_AGENT);
        lo = (unsigned)pk; hi = (unsigned)(pk >> 32);
      } while (((lo ^ tg) & 511u) | ((hi ^ tg) & 511u));
      *(float2*)&hs2[t & 1][pidx(2 * slot)] =
          make_float2(__uint_as_float(lo), __uint_as_float(hi));
    }
    __syncthreads();  // single barrier per step (parity dbuf)

    // ---- quarter-row dot: 64 fp32 MACs, weights register-resident ----
    const float* hsp = &hs2[t & 1][q * QP];
    float a0 = 0.f, a1 = 0.f, a2 = 0.f, a3 = 0.f;
    float a4 = 0.f, a5 = 0.f, a6 = 0.f, a7 = 0.f;
    ACC8(0, 1, 0);   ACC8(2, 3, 8);   ACC8(4, 5, 16);  ACC8(6, 7, 24);
    ACC8(8, 9, 32);  ACC8(10, 11, 40); ACC8(12, 13, 48); ACC8(14, 15, 56);
    float qd = ((a0 + a1) + (a2 + a3)) + ((a4 + a5) + (a6 + a7));
    float d0 = qd + __shfl_xor(qd, 1);   // K-combine butterfly
    float dot = d0 + __shfl_xor(d0, 2);
    float raw = dot + xs[t] * wih + bias;

    // ---- activate own gate, exchange across the 4 gates (16-lane unit group) ----
    float act = (g == 2) ? tanhf_fast(raw) : sigf(raw);
    float v1 = __shfl_xor(act, 4);   // gate g^1
    float v2 = __shfl_xor(act, 8);   // gate g^2
    float v3 = __shfl_xor(act, 12);  // gate g^3
    float ai = pick4(g,     act, v1, v2, v3);  // sigmoid(i)
    float af = pick4(g ^ 1, act, v1, v2, v3);  // sigmoid(f)
    float ag = pick4(g ^ 2, act, v1, v2, v3);  // tanh(g)
    float ao = pick4(g ^ 3, act, v1, v2, v3);  // sigmoid(o)

    float c_new = af * ap_c + ai * ag;
    float h_new = ao * tanhf_fast(c_new);

    if (t < Tn - 1) {
      // ---- allpass h-update + packed publish FIRST (latency-critical) ----
      float nh = kCoeff * (h_new - ap_h) + s1_h;
      unsigned vb = tagf(nh, (unsigned)(t + 1) & 511u);  // self-tagged bits
      unsigned pb = __shfl_xor(vb, 16);                  // partner unit's bits
      if ((tid & 31) == 12) {  // g==3,q==0 of even local unit: one per slot
        const int s = w * 16 + (tid >> 5);  // global slot = u/2
        unsigned long long pk = (unsigned long long)vb |
                                ((unsigned long long)pb << 32);
        __hip_atomic_store(mypub + ((t + 1) & 1) * 128 + s, pk, __ATOMIC_RELAXED,
                           __HIP_MEMORY_SCOPE_AGENT);  // remote WGs (IC)
        *(float2*)&hs2[(t + 1) & 1][pidx(2 * s)] =      // own WG (LDS shortcut)
            make_float2(__uint_as_float(vb), __uint_as_float(pb));
      }
      float nc = kCoeff * (c_new - ap_c) + s1_c;
      s1_h = h_new; s1_c = c_new; ap_h = nh; ap_c = nc;
    } else {
      if (g == 0 && q == 0)      out[201326592 + b * 512 + u] = ap_h;        // ap_final h
      else if (g == 1 && q == 0) out[201326592 + b * 512 + 256 + u] = ap_c;  // ap_final c
    }

    // ---- outputs: (y, states_h, states_c) fp32, fire-and-forget ----
    int o = (b * Tn + t) * Hn + u;
    if (q == 0) {
      if (g == 0)      out[o] = h_new;             // y
      else if (g == 2) out[67108864 + o] = h_new;  // states h
      else if (g == 1) out[134217728 + o] = c_new; // states c
    }
    // no trailing barrier: parity dbuf + publish-after-barrier make it safe
  }
}

extern "C" void kernel_launch(void* const* d_in, const int* in_sizes, int n_in,
                              void* d_out, int out_size, void* d_ws, size_t ws_size,
                              hipStream_t stream) {
  const float* x = (const float*)d_in[0];
  const float* W_ih = (const float*)d_in[1];
  const float* W_hh = (const float*)d_in[2];
  const float* b_ih = (const float*)d_in[3];
  const float* b_hh = (const float*)d_in[4];
  float* out = (float*)d_out;
  unsigned long long* pub = (unsigned long long*)d_ws;

  init_ws<<<64, 256, 0, stream>>>((unsigned int*)d_ws);  // reset tags every launch
  apdl_rnn<<<256, 512, 0, stream>>>(x, W_ih, W_hh, b_ih, b_hh, out, pub);
}